// Round 7
// baseline (3110.529 us; speedup 1.0000x reference)
//
#include <hip/hip_runtime.h>
#include <cstdint>

// Cortex reservoir: embed(perm-gather) -> single-XCD persistent scan in 2-step
// SUPERSTEPS with halo-redundant compute (sync cost amortized 2x) -> chunked GEMM.
//
// Sync protocol (PROVEN in round 5): 32 worker blocks on XCD 0 (shared L2 =
// coherence point). Per superstep: poll 4 neighbor flags (tid 0..3, volatile
// load + buffer_inv), acquire buffer_inv, load state, compute 2 steps in LDS,
// store state, s_waitcnt vmcnt(0) drain, barrier, publish flag. Round 6's
// data-tag spin (256 waves x buffer_inv storm) livelocked -- do NOT sync on data.
//
// Block b owns rows [8b, 8b+8). Superstep g: consumes state of step 2g-1
// (slot g&1), produces step 2g+1 state (slot (g+1)&1); steps 2g and 2g+1 go
// to Achunk. Halo 16 rows/side -> deps b+-1, b+-2.
//
// S and conv counts are exact small integers -> uint8 in LDS; fp32 V. All fp32
// expressions form-identical to rounds 2-5 (bit-identical results).

namespace {

constexpr int TT = 512;
constexpr int DD = 256;
constexpr int CELLS = DD * DD;              // 65536
constexpr long KTOT = 2L * CELLS;           // 131072
constexpr int TB = 128;                     // time-chunk (steps)
constexpr int NCH = TT / TB;                // 4
constexpr int NSUP = TB / 2;                // 64 supersteps per chunk
constexpr int KSLAB = 1024;
constexpr int NSLAB = 128;                  // KTOT / KSLAB
constexpr int NW = 32;                      // worker blocks (one XCD)

constexpr long OFF_TICK = 0;
constexpr long OFF_PERM = 4096;
constexpr long OFF_FLAG = 8192;             // int[32*16]
constexpr long OFF_V  = 12288;              // float[2][CELLS]
constexpr long OFF_SB = OFF_V + 2L * CELLS * 4;
constexpr long OFF_A  = OFF_SB + 2L * CELLS * 4;
constexpr long OFF_P  = OFF_A + (long)TB * KTOT * 4;
constexpr long WS_REQUIRED = OFF_P + (long)NSLAB * TB * 128 * 4;  // ~73 MiB

__device__ __forceinline__ int xcc_id() {
    int x;
    asm volatile("s_getreg_b32 %0, hwreg(HW_REG_XCC_ID, 0, 4)" : "=s"(x));
    return x;
}

__global__ __launch_bounds__(256) void perm_kernel(const float* __restrict__ We,
                                                   int* __restrict__ perm) {
    int idx = blockIdx.x * 256 + threadIdx.x;       // over 1024*1024
    if (We[idx] > 0.5f) perm[idx >> 10] = idx & 1023;
}

__global__ __launch_bounds__(256) void zero_state(float* __restrict__ Vb) {
    Vb[blockIdx.x * 256 + threadIdx.x] = 0.0f;      // zero Vb[2] and Sb[2] (contiguous)
}

__global__ void ctrl_init(int* __restrict__ flags, int* __restrict__ ticket, int g0) {
    int i = threadIdx.x;
    if (i < NW) flags[i * 16] = g0;
    if (i == NW) *ticket = 0;
}

// Persistent superstep scan for one chunk (NSUP supersteps = TB steps).
__global__ __launch_bounds__(256) void scan_chunk(
    const float* __restrict__ X,
    const int* __restrict__ perm,
    const float* __restrict__ mc,
    const float* __restrict__ mf,
    float* __restrict__ Vb,       // [2][CELLS] step-state ping-pong
    float* __restrict__ Sb,       // [2][CELLS]
    float* __restrict__ Achunk,   // [TB][KTOT]
    int* __restrict__ flags,      // [32*16]
    int* __restrict__ ticket,
    int t0)
{
#pragma clang fp contract(off)
    __shared__ unsigned char S0[40][DD];   // S_{2g-1}, rows 8b-16 .. 8b+23
    __shared__ unsigned char S1[24][DD];   // S_{2g},   rows 8b-8  .. 8b+15
    __shared__ unsigned char C5[24][DD];   // vertical 5-counts
    __shared__ unsigned char C9[24][DD];   // vertical dilated 9-counts
    __shared__ float V0[24][DD];           // V (in-place A-step update)
    __shared__ float utA[96];              // input drive, 3 coarse rows (step A)
    __shared__ float utB[32];              // own coarse row (step B)
    __shared__ int sh_b;
    __shared__ int sh_bail;

    const int tid = threadIdx.x;
    if (tid == 0) {
        int tk = -1;
        if (xcc_id() == 0)
            tk = __hip_atomic_fetch_add(ticket, 1, __ATOMIC_RELAXED,
                                        __HIP_MEMORY_SCOPE_AGENT);
        sh_b = tk;
        sh_bail = 0;
    }
    __syncthreads();
    const int b = sh_b;
    if (b < 0 || b >= NW) return;   // uniform per block

    const int x = tid;
    const int g0 = t0 >> 1;
    // neighbor flag slot for polling threads 0..3
    const int nbi = (tid == 0) ? ((b + 30) & 31) : (tid == 1) ? ((b + 31) & 31)
                  : (tid == 2) ? ((b + 1) & 31)  : ((b + 2) & 31);
    volatile int* nbf = (volatile int*)&flags[nbi * 16];
    volatile int* myf = (volatile int*)&flags[b * 16];

    // mf is constant: preload the 24 region rows into registers once.
    float mfr[24];
#pragma unroll
    for (int ra = 0; ra < 24; ++ra) {
        int grow = (b * 8 - 8 + ra) & 255;
        mfr[ra] = mf[grow * DD + x];
    }

    for (int g = g0; g < g0 + NSUP; ++g) {
        // ---- 1. wait for neighbors to have published superstep g-1 state ----
        if (tid < 4) {
            long gd = 0;
            while (*nbf < g) {
                asm volatile("buffer_inv" ::: "memory");
                if (++gd > (1L << 22)) { sh_bail = 1; break; }
            }
        }
        __syncthreads();
        if (sh_bail) { if (tid == 0) *myf = g0 + NSUP; break; }
        asm volatile("buffer_inv" ::: "memory");   // acquire: drop stale L1 lines

        const int cs = g & 1, ns = (g + 1) & 1;    // state slots
        const float* Vcur = Vb + (long)cs * CELLS;
        const float* Scur = Sb + (long)cs * CELLS;

        // ---- 2. load state + input drives ----
        for (int rs = 0; rs < 40; ++rs) {
            int grow = (b * 8 - 16 + rs) & 255;
            S0[rs][x] = (unsigned char)(Scur[grow * DD + x] > 0.5f);
        }
        for (int ra = 0; ra < 24; ++ra) {
            int grow = (b * 8 - 8 + ra) & 255;
            V0[ra][x] = Vcur[grow * DD + x];
        }
        if (tid < 96) {
            int jr = tid >> 5, cx = tid & 31;
            int cy = ((b * 8 - 8 + jr * 8) & 255) >> 3;
            int c = cy * 32 + cx;
            utA[tid] = tanhf(X[(long)(2 * g) * 1024 + perm[c]] * mc[c]);
        } else if (tid < 128) {
            int cx = tid - 96;
            int c = b * 32 + cx;
            utB[cx] = tanhf(X[(long)(2 * g + 1) * 1024 + perm[c]] * mc[c]);
        }
        __syncthreads();

        // ---- 3. step A vertical counts (sliding windows, exact ints) ----
        {
            int w5 = 0;
#pragma unroll
            for (int r = 6; r <= 10; ++r) w5 += S0[r][x];
            int w9e = 0, w9o = 0;
#pragma unroll
            for (int r = 0; r <= 16; r += 2) w9e += S0[r][x];
#pragma unroll
            for (int r = 1; r <= 17; r += 2) w9o += S0[r][x];
            for (int ra = 0; ra < 24; ++ra) {
                C5[ra][x] = (unsigned char)w5;
                C9[ra][x] = (unsigned char)((ra & 1) ? w9o : w9e);
                if (ra < 23) w5 += S0[ra + 11][x] - S0[ra + 6][x];
                if (ra < 22) {
                    if (ra & 1) w9o += S0[ra + 18][x] - S0[ra][x];
                    else        w9e += S0[ra + 18][x] - S0[ra][x];
                }
            }
        }
        __syncthreads();

        // ---- 4. step A horizontal + V update on 24 rows (X[2g]) ----
        for (int ra = 0; ra < 24; ++ra) {
            int h5 = C5[ra][(x-2)&255] + C5[ra][(x-1)&255] + C5[ra][x]
                   + C5[ra][(x+1)&255] + C5[ra][(x+2)&255];
            int h9 = C9[ra][(x-8)&255] + C9[ra][(x-6)&255] + C9[ra][(x-4)&255]
                   + C9[ra][(x-2)&255] + C9[ra][x]
                   + C9[ra][(x+2)&255] + C9[ra][(x+4)&255]
                   + C9[ra][(x+6)&255] + C9[ra][(x+8)&255];
            float avg5 = (float)h5 * (1.0f/25.0f);
            float avg9 = (float)h9 * (1.0f/81.0f);
            float lat = avg5 - 0.5f * avg9;
            float u = utA[(ra >> 3) * 32 + (x >> 3)] * mfr[ra];
            float V1 = 0.9f * V0[ra][x] + 0.5f * u;
            float V2 = (V1 >= 0.1f) ? ((V1 + 0.5f * u) + lat) : V1;
            V2 = fminf(V2, 1.0f);
            const bool sp = V2 > 0.75f;
            V0[ra][x] = sp ? 0.0f : V2;
            S1[ra][x] = sp ? 1 : 0;
        }
        __syncthreads();

        // ---- 5. step B vertical counts over S1 (own 8 rows) ----
        {
            int w5 = 0;
#pragma unroll
            for (int r = 6; r <= 10; ++r) w5 += S1[r][x];
            int w9e = 0, w9o = 0;
#pragma unroll
            for (int r = 0; r <= 16; r += 2) w9e += S1[r][x];
#pragma unroll
            for (int r = 1; r <= 17; r += 2) w9o += S1[r][x];
            for (int rb = 0; rb < 8; ++rb) {
                C5[rb][x] = (unsigned char)w5;   // reuse C buffers (barriered)
                C9[rb][x] = (unsigned char)((rb & 1) ? w9o : w9e);
                if (rb < 7) w5 += S1[rb + 11][x] - S1[rb + 6][x];
                if (rb < 6) {
                    if (rb & 1) w9o += S1[rb + 18][x] - S1[rb][x];
                    else        w9e += S1[rb + 18][x] - S1[rb][x];
                }
            }
        }
        __syncthreads();

        // ---- 6. step B horizontal + V update on own 8 rows (X[2g+1]) ----
        float aV[8], aS[8];
        float* Vnx = Vb + (long)ns * CELLS;
        float* Snx = Sb + (long)ns * CELLS;
#pragma unroll
        for (int rb = 0; rb < 8; ++rb) {
            int h5 = C5[rb][(x-2)&255] + C5[rb][(x-1)&255] + C5[rb][x]
                   + C5[rb][(x+1)&255] + C5[rb][(x+2)&255];
            int h9 = C9[rb][(x-8)&255] + C9[rb][(x-6)&255] + C9[rb][(x-4)&255]
                   + C9[rb][(x-2)&255] + C9[rb][x]
                   + C9[rb][(x+2)&255] + C9[rb][(x+4)&255]
                   + C9[rb][(x+6)&255] + C9[rb][(x+8)&255];
            float avg5 = (float)h5 * (1.0f/25.0f);
            float avg9 = (float)h9 * (1.0f/81.0f);
            float lat = avg5 - 0.5f * avg9;
            float u = utB[x >> 3] * mfr[rb + 8];
            float V1 = 0.9f * V0[rb + 8][x] + 0.5f * u;
            float V2 = (V1 >= 0.1f) ? ((V1 + 0.5f * u) + lat) : V1;
            V2 = fminf(V2, 1.0f);
            const bool sp = V2 > 0.75f;
            aV[rb] = sp ? 0.0f : V2;
            aS[rb] = sp ? 1.0f : 0.0f;
            int grow = b * 8 + rb;
            Vnx[grow * DD + x] = aV[rb];
            Snx[grow * DD + x] = aS[rb];
        }

        // ---- 7. publish: drain state stores to shared L2, then flag ----
        asm volatile("s_waitcnt vmcnt(0)" ::: "memory");
        __syncthreads();
        if (tid == 0) *myf = g + 1;

        // ---- 8. off-critical-path: Achunk rows for steps 2g, 2g+1 ----
        float* ArA = Achunk + (long)(2 * g - t0) * KTOT;
        float* ArB = Achunk + (long)(2 * g + 1 - t0) * KTOT;
#pragma unroll
        for (int rb = 0; rb < 8; ++rb) {
            int grow = b * 8 + rb;
            ArA[grow * DD + x] = V0[rb + 8][x];
            ArA[CELLS + grow * DD + x] = (float)S1[rb + 8][x];
            ArB[grow * DD + x] = aV[rb];
            ArB[CELLS + grow * DD + x] = aS[rb];
        }
    }
}

// Split-K fp32 GEMM on one chunk: 64 t x 128 o x KSLAB k per block. Grid (2, NSLAB).
__global__ __launch_bounds__(256) void gemm_partial(
    const float* __restrict__ A,   // chunk [TB][KTOT]
    const float* __restrict__ B,   // W_out [128][KTOT]
    float* __restrict__ P)         // [NSLAB][TB][128]
{
    __shared__ float As[16][68];   // [k][t]
    __shared__ float Bs[16][132];  // [k][o]
    const int tid = threadIdx.x;
    const int t0 = blockIdx.x * 64;
    const long k0 = (long)blockIdx.y * KSLAB;
    const int tx = tid & 15;       // 8 o's each
    const int ty = tid >> 4;       // 4 t's each

    float acc[4][8];
#pragma unroll
    for (int i = 0; i < 4; ++i)
#pragma unroll
        for (int j = 0; j < 8; ++j) acc[i][j] = 0.0f;

    const int ar = tid >> 2, ac = (tid & 3) * 4;   // A: 64 rows x 16 k
    const int br = tid >> 1, bc = (tid & 1) * 8;   // B: 128 rows x 16 k

    for (int kc = 0; kc < KSLAB; kc += 16) {
        float4 av = *(const float4*)&A[(long)(t0 + ar) * KTOT + k0 + kc + ac];
        As[ac+0][ar] = av.x; As[ac+1][ar] = av.y; As[ac+2][ar] = av.z; As[ac+3][ar] = av.w;
        float4 bv0 = *(const float4*)&B[(long)br * KTOT + k0 + kc + bc];
        float4 bv1 = *(const float4*)&B[(long)br * KTOT + k0 + kc + bc + 4];
        Bs[bc+0][br] = bv0.x; Bs[bc+1][br] = bv0.y; Bs[bc+2][br] = bv0.z; Bs[bc+3][br] = bv0.w;
        Bs[bc+4][br] = bv1.x; Bs[bc+5][br] = bv1.y; Bs[bc+6][br] = bv1.z; Bs[bc+7][br] = bv1.w;
        __syncthreads();
#pragma unroll
        for (int kk = 0; kk < 16; ++kk) {
            float4 a4  = *(const float4*)&As[kk][ty*4];
            float4 b40 = *(const float4*)&Bs[kk][tx*8];
            float4 b41 = *(const float4*)&Bs[kk][tx*8+4];
            float a[4] = {a4.x, a4.y, a4.z, a4.w};
            float b[8] = {b40.x, b40.y, b40.z, b40.w, b41.x, b41.y, b41.z, b41.w};
#pragma unroll
            for (int i = 0; i < 4; ++i)
#pragma unroll
                for (int j = 0; j < 8; ++j) acc[i][j] += a[i] * b[j];
        }
        __syncthreads();
    }
#pragma unroll
    for (int i = 0; i < 4; ++i)
#pragma unroll
        for (int j = 0; j < 8; ++j)
            P[((long)blockIdx.y * TB + t0 + ty*4 + i) * 128 + tx*8 + j] = acc[i][j];
}

// Sum NSLAB partials for one chunk, add bias, write out rows [c*TB, (c+1)*TB).
__global__ __launch_bounds__(256) void reduce_kernel(
    const float* __restrict__ P, const float* __restrict__ bias,
    float* __restrict__ out, int c)
{
    int tid = blockIdx.x * 256 + threadIdx.x;      // 16384 = TB*128
    int o = tid & 127;
    float acc = 0.0f;
#pragma unroll 8
    for (int j = 0; j < NSLAB; ++j) acc += P[(long)j * (TB * 128) + tid];
    out[(long)c * (TB * 128) + tid] = acc + bias[o];
}

} // namespace

extern "C" void kernel_launch(void* const* d_in, const int* in_sizes, int n_in,
                              void* d_out, int out_size, void* d_ws, size_t ws_size,
                              hipStream_t stream)
{
    const float* X  = (const float*)d_in[0];   // [512,1024]
    const float* We = (const float*)d_in[1];   // [1024,1024] permuted identity
    const float* mc = (const float*)d_in[2];   // [32,32]
    const float* mf = (const float*)d_in[3];   // [256,256]
    const float* Wo = (const float*)d_in[4];   // [128,2,256,256]
    const float* bo = (const float*)d_in[5];   // [128]
    float* out = (float*)d_out;                // [512,128] fp32

    if (ws_size < (size_t)WS_REQUIRED) return;  // fail loudly (wrong result, no fault)

    char* ws = (char*)d_ws;
    int*   ticket = (int*)(ws + OFF_TICK);
    int*   perm   = (int*)(ws + OFF_PERM);
    int*   flags  = (int*)(ws + OFF_FLAG);
    float* Vb     = (float*)(ws + OFF_V);
    float* Sb     = (float*)(ws + OFF_SB);
    float* Achunk = (float*)(ws + OFF_A);
    float* P      = (float*)(ws + OFF_P);

    perm_kernel<<<4096, 256, 0, stream>>>(We, perm);
    zero_state<<<1024, 256, 0, stream>>>(Vb);   // zeros Vb[2] and Sb[2] (contiguous)
    for (int c = 0; c < NCH; ++c) {
        ctrl_init<<<1, 64, 0, stream>>>(flags, ticket, c * NSUP);
        scan_chunk<<<1024, 256, 0, stream>>>(X, perm, mc, mf, Vb, Sb, Achunk,
                                             flags, ticket, c * TB);
        gemm_partial<<<dim3(2, NSLAB), 256, 0, stream>>>(Achunk, Wo, P);
        reduce_kernel<<<64, 256, 0, stream>>>(P, bo, out, c);
    }
}

// Round 9
// 2617.703 us; speedup vs baseline: 1.1883x; 1.1883x over previous
//
#include <hip/hip_runtime.h>
#include <cstdint>

// Cortex reservoir: embed(perm-gather) -> single-XCD persistent neighbor-synced
// spiking scan -> chunked dense readout GEMM.
//
// Scan coherence design (gfx950, 8 XCDs): 32 worker blocks confined to XCD 0
// (HW_REG_XCC_ID + ticket), ONE per CU; the XCD-0 L2 is the coherence point.
//   publish = S stores -> s_waitcnt vmcnt(0) drain -> barrier -> volatile flag store
//   poll    = volatile load + buffer_inv in spin loop (PROVEN r5; r8's sc0-load
//             poll never saw updates -> sc0 loads do NOT bypass L1 on gfx950)
// Block b owns rows [8b, 8b+8); radius 8 -> deps only b+-1 (2 flags).
//
// ws layout (~73 MiB):
//   OFF_PERM  : perm int[1024]
//   OFF_FLAG  : flags int[32*16] (padded) + ticket at [1024]
//   OFF_VSAVE : V snapshot float[65536]
//   OFF_S     : S ping-pong float[2][65536]
//   OFF_A     : A chunk float[128][131072]
//   OFF_P     : split-K partials float[128][128][128]

namespace {

constexpr int TT = 512;
constexpr int DD = 256;
constexpr int CELLS = DD * DD;              // 65536
constexpr long KTOT = 2L * CELLS;           // 131072
constexpr int TB = 128;                     // time-chunk
constexpr int NCH = TT / TB;                // 4
constexpr int KSLAB = 1024;
constexpr int NSLAB = 128;                  // KTOT / KSLAB
constexpr int NW = 32;                      // worker blocks (one XCD, 1/CU)

constexpr long OFF_PERM = 0;
constexpr long OFF_FLAG = 4096;
constexpr long OFF_VSAVE = OFF_FLAG + 8192;
constexpr long OFF_S = OFF_VSAVE + (long)CELLS * 4;
constexpr long OFF_A = OFF_S + 2L * CELLS * 4;
constexpr long OFF_P = OFF_A + (long)TB * KTOT * 4;
constexpr long WS_REQUIRED = OFF_P + (long)NSLAB * TB * 128 * 4;  // ~72.8 MiB

__device__ __forceinline__ int xcc_id() {
    int x;
    asm volatile("s_getreg_b32 %0, hwreg(HW_REG_XCC_ID, 0, 4)" : "=s"(x));
    return x;
}

__global__ __launch_bounds__(256) void perm_kernel(const float* __restrict__ We,
                                                   int* __restrict__ perm) {
    int idx = blockIdx.x * 256 + threadIdx.x;       // over 1024*1024
    if (We[idx] > 0.5f) perm[idx >> 10] = idx & 1023;
}

__global__ void ctrl_init(int* __restrict__ flags, int v) {
    int i = threadIdx.x;
    if (i < NW) flags[i * 16] = v;
    if (i == NW) flags[1024] = 0;   // ticket counter
}

// Persistent scan for one 128-step chunk. 1024 blocks launched; 32 workers on
// XCD 0 (ticket-selected), each owns 8 rows. Block b at step t needs S_{t-1}
// from workers b+-1 only (circular; radius 8 == strip height).
__global__ __launch_bounds__(256) void scan_chunk(
    const float* __restrict__ X,
    const int* __restrict__ perm,
    const float* __restrict__ mc,
    const float* __restrict__ mf,
    float* __restrict__ Sst,      // ping-pong [2][CELLS]
    float* __restrict__ Vsave,    // [CELLS]
    float* __restrict__ Achunk,   // [TB][KTOT]
    int* __restrict__ flags,      // padded [32*16]; ticket at [1024]
    int t0)
{
#pragma clang fp contract(off)
    __shared__ float Sld[24][DD];   // rows y0-8 .. y0+15 of S_{t-1}
    __shared__ float C5[8][DD];     // vertical 5-sums for the 8 target rows
    __shared__ float C9[8][DD];     // vertical dilated 9-sums
    __shared__ float ut[32];        // per-step input drive (own coarse row)
    __shared__ int sh_b;
    __shared__ int sh_bail;

    const int tid = threadIdx.x;
    if (tid == 0) {
        int tk = -1;
        if (xcc_id() == 0)
            tk = __hip_atomic_fetch_add(&flags[1024], 1, __ATOMIC_RELAXED,
                                        __HIP_MEMORY_SCOPE_AGENT);
        sh_b = tk;
        sh_bail = 0;
    }
    __syncthreads();
    const int b = sh_b;
    if (b < 0 || b >= NW) return;   // uniform per block

    const int y0 = b * 8;           // 8-row strip == one coarse row (cy == b)
    const int x = tid;
    // neighbor flag slot for polling threads 0..1
    const int nbi = (tid == 0) ? ((b + 31) & 31) : ((b + 1) & 31);
    volatile int* nbf = (volatile int*)&flags[nbi * 16];
    volatile int* myf = (volatile int*)&flags[b * 16];

    // V state lives in registers for the whole chunk.
    float V[8];
    if (t0 == 0) {
#pragma unroll
        for (int ry = 0; ry < 8; ++ry) V[ry] = 0.0f;
    } else {
#pragma unroll
        for (int ry = 0; ry < 8; ++ry) V[ry] = Vsave[(y0 + ry) * DD + x];
    }
    float mfv[8];
#pragma unroll
    for (int ry = 0; ry < 8; ++ry) mfv[ry] = mf[(y0 + ry) * DD + x];

    for (int t = t0; t < t0 + TB; ++t) {
        // 1. wait for neighbors to publish S_{t-1} (flag == completed steps).
        //    Threads 0..1 poll one neighbor each (volatile load + buffer_inv).
        if (tid < 2) {
            long g = 0;
            while (*nbf < t) {
                asm volatile("buffer_inv" ::: "memory");  // drop stale L1 lines
                if (++g > (1L << 23)) { sh_bail = 1; break; }
            }
        }
        __syncthreads();
        if (sh_bail) {              // let neighbors terminate too, then abandon
            if (tid == 0) *myf = t0 + TB;
            break;
        }
        // acquire within XCD: drop stale L1 lines; shared L2 is authoritative
        asm volatile("buffer_inv" ::: "memory");

        // 2. input drive for this step (exact: mc in {0,1}); coarse row == b
        if (tid < 32) {
            int c = b * 32 + tid;
            ut[tid] = tanhf(X[(long)t * 1024 + perm[c]] * mc[c]);
        }

        // 3. halo load: 24 rows of S_{t-1} (slot (t+1)&1)
        const float* Sprev = Sst + (long)((t + 1) & 1) * CELLS;
        for (int i = tid; i < 24 * 64; i += 256) {
            int rr = i >> 6;
            int x4 = (i & 63) << 2;
            float4 s = make_float4(0.f, 0.f, 0.f, 0.f);
            if (t > 0) {
                int gy = (y0 - 8 + rr) & 255;
                s = *(const float4*)&Sprev[gy * DD + x4];
            }
            *(float4*)&Sld[rr][x4] = s;
        }
        __syncthreads();

        // 4. vertical sums (exact integer counts in fp32)
#pragma unroll
        for (int ry = 0; ry < 8; ++ry) {
            int r = 8 + ry;
            C5[ry][x] = Sld[r-2][x] + Sld[r-1][x] + Sld[r][x] + Sld[r+1][x] + Sld[r+2][x];
            C9[ry][x] = Sld[r-8][x] + Sld[r-6][x] + Sld[r-4][x] + Sld[r-2][x] + Sld[r][x]
                      + Sld[r+2][x] + Sld[r+4][x] + Sld[r+6][x] + Sld[r+8][x];
        }
        __syncthreads();

        // 5. horizontal sums + V update (V in regs)
        float Vn[8], Sn[8];
        const float um = ut[x >> 3];
#pragma unroll
        for (int ry = 0; ry < 8; ++ry) {
            float h5 = C5[ry][(x-2)&255] + C5[ry][(x-1)&255] + C5[ry][x]
                     + C5[ry][(x+1)&255] + C5[ry][(x+2)&255];
            float h9 = C9[ry][(x-8)&255] + C9[ry][(x-6)&255] + C9[ry][(x-4)&255]
                     + C9[ry][(x-2)&255] + C9[ry][x]
                     + C9[ry][(x+2)&255] + C9[ry][(x+4)&255]
                     + C9[ry][(x+6)&255] + C9[ry][(x+8)&255];
            float avg5 = h5 * (1.0f/25.0f);
            float avg9 = h9 * (1.0f/81.0f);
            float lat = avg5 - 0.5f * avg9;          // EXC*avg5 + INH*avg9
            float u = um * mfv[ry];                  // exact: mf in {0,1}
            float V1 = 0.9f * V[ry] + 0.5f * u;      // DECAY*V + SPLIT*x
            float V2 = (V1 >= 0.1f) ? ((V1 + 0.5f * u) + lat) : V1;
            V2 = fminf(V2, 1.0f);
            const bool sp = V2 > 0.75f;
            Vn[ry] = sp ? 0.0f : V2;
            Sn[ry] = sp ? 1.0f : 0.0f;
        }
        float* Scur = Sst + (long)(t & 1) * CELLS;
#pragma unroll
        for (int ry = 0; ry < 8; ++ry) Scur[(y0 + ry) * DD + x] = Sn[ry];

        // 6. release within XCD: drain own stores to the write-through L2, flag.
        asm volatile("s_waitcnt vmcnt(0)" ::: "memory");
        __syncthreads();                 // all waves drained
        if (tid == 0) *myf = t + 1;      // plain volatile store -> L2

        // 7. off-critical-path: readout rows + register rotate
        float* Arow = Achunk + (long)(t - t0) * KTOT;
#pragma unroll
        for (int ry = 0; ry < 8; ++ry) {
            Arow[(y0 + ry) * DD + x] = Vn[ry];
            Arow[CELLS + (y0 + ry) * DD + x] = Sn[ry];
            V[ry] = Vn[ry];
        }
    }

    // save V for next chunk
#pragma unroll
    for (int ry = 0; ry < 8; ++ry) Vsave[(y0 + ry) * DD + x] = V[ry];
}

// Split-K fp32 GEMM on one chunk: 64 t x 128 o x KSLAB k per block. Grid (2, NSLAB).
__global__ __launch_bounds__(256) void gemm_partial(
    const float* __restrict__ A,   // chunk [TB][KTOT]
    const float* __restrict__ B,   // W_out [128][KTOT]
    float* __restrict__ P)         // [NSLAB][TB][128]
{
    __shared__ float As[16][68];   // [k][t]
    __shared__ float Bs[16][132];  // [k][o]
    const int tid = threadIdx.x;
    const int t0 = blockIdx.x * 64;
    const long k0 = (long)blockIdx.y * KSLAB;
    const int tx = tid & 15;       // 8 o's each
    const int ty = tid >> 4;       // 4 t's each

    float acc[4][8];
#pragma unroll
    for (int i = 0; i < 4; ++i)
#pragma unroll
        for (int j = 0; j < 8; ++j) acc[i][j] = 0.0f;

    const int ar = tid >> 2, ac = (tid & 3) * 4;   // A: 64 rows x 16 k
    const int br = tid >> 1, bc = (tid & 1) * 8;   // B: 128 rows x 16 k

    for (int kc = 0; kc < KSLAB; kc += 16) {
        float4 av = *(const float4*)&A[(long)(t0 + ar) * KTOT + k0 + kc + ac];
        As[ac+0][ar] = av.x; As[ac+1][ar] = av.y; As[ac+2][ar] = av.z; As[ac+3][ar] = av.w;
        float4 bv0 = *(const float4*)&B[(long)br * KTOT + k0 + kc + bc];
        float4 bv1 = *(const float4*)&B[(long)br * KTOT + k0 + kc + bc + 4];
        Bs[bc+0][br] = bv0.x; Bs[bc+1][br] = bv0.y; Bs[bc+2][br] = bv0.z; Bs[bc+3][br] = bv0.w;
        Bs[bc+4][br] = bv1.x; Bs[bc+5][br] = bv1.y; Bs[bc+6][br] = bv1.z; Bs[bc+7][br] = bv1.w;
        __syncthreads();
#pragma unroll
        for (int kk = 0; kk < 16; ++kk) {
            float4 a4  = *(const float4*)&As[kk][ty*4];
            float4 b40 = *(const float4*)&Bs[kk][tx*8];
            float4 b41 = *(const float4*)&Bs[kk][tx*8+4];
            float a[4] = {a4.x, a4.y, a4.z, a4.w};
            float b[8] = {b40.x, b40.y, b40.z, b40.w, b41.x, b41.y, b41.z, b41.w};
#pragma unroll
            for (int i = 0; i < 4; ++i)
#pragma unroll
                for (int j = 0; j < 8; ++j) acc[i][j] += a[i] * b[j];
        }
        __syncthreads();
    }
#pragma unroll
    for (int i = 0; i < 4; ++i)
#pragma unroll
        for (int j = 0; j < 8; ++j)
            P[((long)blockIdx.y * TB + t0 + ty*4 + i) * 128 + tx*8 + j] = acc[i][j];
}

// Sum NSLAB partials for one chunk, add bias, write out rows [c*TB, (c+1)*TB).
__global__ __launch_bounds__(256) void reduce_kernel(
    const float* __restrict__ P, const float* __restrict__ bias,
    float* __restrict__ out, int c)
{
    int tid = blockIdx.x * 256 + threadIdx.x;      // 16384 = TB*128
    int o = tid & 127;
    float acc = 0.0f;
#pragma unroll 8
    for (int j = 0; j < NSLAB; ++j) acc += P[(long)j * (TB * 128) + tid];
    out[(long)c * (TB * 128) + tid] = acc + bias[o];
}

} // namespace

extern "C" void kernel_launch(void* const* d_in, const int* in_sizes, int n_in,
                              void* d_out, int out_size, void* d_ws, size_t ws_size,
                              hipStream_t stream)
{
    const float* X  = (const float*)d_in[0];   // [512,1024]
    const float* We = (const float*)d_in[1];   // [1024,1024] permuted identity
    const float* mc = (const float*)d_in[2];   // [32,32]
    const float* mf = (const float*)d_in[3];   // [256,256]
    const float* Wo = (const float*)d_in[4];   // [128,2,256,256]
    const float* bo = (const float*)d_in[5];   // [128]
    float* out = (float*)d_out;                // [512,128] fp32

    if (ws_size < (size_t)WS_REQUIRED) return;  // fail loudly (wrong result, no fault)

    char* ws = (char*)d_ws;
    int*   perm   = (int*)(ws + OFF_PERM);
    int*   flags  = (int*)(ws + OFF_FLAG);
    float* Vsave  = (float*)(ws + OFF_VSAVE);
    float* Sst    = (float*)(ws + OFF_S);
    float* Achunk = (float*)(ws + OFF_A);
    float* P      = (float*)(ws + OFF_P);

    perm_kernel<<<4096, 256, 0, stream>>>(We, perm);
    for (int c = 0; c < NCH; ++c) {
        ctrl_init<<<1, 64, 0, stream>>>(flags, c * TB);
        scan_chunk<<<1024, 256, 0, stream>>>(X, perm, mc, mf, Sst, Vsave, Achunk,
                                             flags, c * TB);
        gemm_partial<<<dim3(2, NSLAB), 256, 0, stream>>>(Achunk, Wo, P);
        reduce_kernel<<<64, 256, 0, stream>>>(P, bo, out, c);
    }
}